// Round 9
// baseline (134.477 us; speedup 1.0000x reference)
//
#include <hip/hip_runtime.h>
#include <math.h>

// CSR segment-max graph pooling:
//   out[i,:] = max over e in [indptr[i], indptr[i+1]) of x[indices[e], :]
// N=100000 nodes, D=32 f32 features, uniform degree 16.
//
// Round-9: slice-phased gather for L2 locality. x (12.8 MB) does not fit a
// 4 MB per-XCD L2, so random gathers miss ~70% to L3. Sweep x in 8 slices
// (~1.6 MB each): each thread holds its 16 indices in registers and, per
// slice, gathers only the edges whose row falls in the slice (predicated).
// All waves sweep slices in the same order -> chip-wide in-flight working
// set ~1-2 slices -> gathers become L2 hits. No sync needed: correctness
// is order-independent, locality is statistical. Baseline r8 structure
// otherwise (speculative idx loads, 8 lanes/node, nontemporal store).

typedef float fv4 __attribute__((ext_vector_type(4)));

#define LANES_PER_NODE 8
#define NODES_PER_BLOCK 32   // 256 threads / 8 lanes
#define NSLICES 8

static __device__ __forceinline__ fv4 fmax4(fv4 a, fv4 b) {
    fv4 r;
    r.x = fmaxf(a.x, b.x);
    r.y = fmaxf(a.y, b.y);
    r.z = fmaxf(a.z, b.z);
    r.w = fmaxf(a.w, b.w);
    return r;
}

__global__ __launch_bounds__(256) void seg_max_kernel(
    const float* __restrict__ x,
    const int* __restrict__ indptr,
    const int* __restrict__ indices,
    float* __restrict__ out,
    int n_nodes,
    int n_edges,
    int slice_w)          // ceil(n_rows / NSLICES), n_rows = x rows
{
    const int c    = threadIdx.x & (LANES_PER_NODE - 1);   // 16B chunk 0..7
    const int node = blockIdx.x * NODES_PER_BLOCK + (threadIdx.x >> 3);
    if (node >= n_nodes) return;

    const fv4* __restrict__ x4 = reinterpret_cast<const fv4*>(x);

    fv4 acc0 = { -INFINITY, -INFINITY, -INFINITY, -INFINITY };
    fv4 acc1 = acc0, acc2 = acc0, acc3 = acc0;

    // Speculation guard uses kernel args only (no memory dependency):
    // uniform DEG=16 CSR has indptr[i] == 16*i.
    const bool spec_ok = ((long long)node * 16 + 16 <= (long long)n_edges);

    bool fast = false;
    if (spec_ok) {
        // Speculative index loads: issued with no indptr dependency.
        const int4* __restrict__ idx4 =
            reinterpret_cast<const int4*>(indices) + node * 4;
        const int4 i0 = idx4[0];
        const int4 i1 = idx4[1];
        const int4 i2 = idx4[2];
        const int4 i3 = idx4[3];

        // Validate the speculation (overlaps with the index loads).
        const int start = indptr[node];
        const int end   = indptr[node + 1];
        fast = (start == node * 16) && (end == start + 16);

        if (fast) {
            const int r0 = i0.x, r1 = i0.y, r2  = i0.z, r3  = i0.w;
            const int r4 = i1.x, r5 = i1.y, r6  = i1.z, r7  = i1.w;
            const int r8 = i2.x, r9 = i2.y, r10 = i2.z, r11 = i2.w;
            const int r12 = i3.x, r13 = i3.y, r14 = i3.z, r15 = i3.w;

            // Sweep x in NSLICES slices; gather an edge only in the slice
            // containing its row. 4 accumulators cut the dependent fmax
            // chain; loads within a slice are independent.
#define GATHER_IF(r, A) \
            if ((r) >= lo && (r) < hi) \
                A = fmax4(A, x4[(r) * LANES_PER_NODE + c]);

            #pragma unroll
            for (int s = 0; s < NSLICES; ++s) {
                const int lo = s * slice_w;
                const int hi = lo + slice_w;
                GATHER_IF(r0,  acc0)
                GATHER_IF(r1,  acc1)
                GATHER_IF(r2,  acc2)
                GATHER_IF(r3,  acc3)
                GATHER_IF(r4,  acc0)
                GATHER_IF(r5,  acc1)
                GATHER_IF(r6,  acc2)
                GATHER_IF(r7,  acc3)
                GATHER_IF(r8,  acc0)
                GATHER_IF(r9,  acc1)
                GATHER_IF(r10, acc2)
                GATHER_IF(r11, acc3)
                GATHER_IF(r12, acc0)
                GATHER_IF(r13, acc1)
                GATHER_IF(r14, acc2)
                GATHER_IF(r15, acc3)
            }
#undef GATHER_IF
        }
    }

    if (!fast) {
        // Generic CSR fallback (any degree / alignment).
        const int start = indptr[node];
        const int end   = indptr[node + 1];
        for (int e = start; e < end; ++e) {
            const int row = indices[e];
            acc0 = fmax4(acc0, x4[row * LANES_PER_NODE + c]);
        }
    }

    const fv4 acc = fmax4(fmax4(acc0, acc1), fmax4(acc2, acc3));

    // Write-once output: nontemporal so it doesn't evict x from L2.
    __builtin_nontemporal_store(
        acc, reinterpret_cast<fv4*>(out) + node * LANES_PER_NODE + c);
}

extern "C" void kernel_launch(void* const* d_in, const int* in_sizes, int n_in,
                              void* d_out, int out_size, void* d_ws, size_t ws_size,
                              hipStream_t stream) {
    const float* x       = (const float*)d_in[0];
    const int*   indptr  = (const int*)d_in[1];
    const int*   indices = (const int*)d_in[2];
    float*       out     = (float*)d_out;

    const int n_nodes = in_sizes[1] - 1;        // indptr has N+1 entries
    const int n_edges = in_sizes[2];
    const int n_rows  = in_sizes[0] / 32;       // x is [n_rows, 32] f32
    const int slice_w = (n_rows + NSLICES - 1) / NSLICES;

    const int grid = (n_nodes + NODES_PER_BLOCK - 1) / NODES_PER_BLOCK;
    seg_max_kernel<<<grid, 256, 0, stream>>>(x, indptr, indices, out,
                                             n_nodes, n_edges, slice_w);
}

// Round 10
// 90.468 us; speedup vs baseline: 1.4865x; 1.4865x over previous
//
#include <hip/hip_runtime.h>
#include <math.h>

// CSR segment-max graph pooling:
//   out[i,:] = max over e in [indptr[i], indptr[i+1]) of x[indices[e], :]
// N=100000 nodes, D=32 f32 features, uniform degree 16.
//
// Round-10: revert to the measured-best round-1 kernel (91.0 us total,
// kernel ~42 us). Config-space results: ILP16/16w = 42 us (r1/r8);
// ILP8/32w = 45 us (r7); slice-phased ILP2 = 71-77 us (r9). The kernel is
// memory-queue-bound on random 128B gathers (~4.9 TB/s effective); the
// bytes-in-flight per CU (~262 KB) is VGPR-capacity-saturated in all fast
// variants, so extra occupancy/ILP/locality tricks all netted <= 0.
// Keep the simplest max-ILP form: 8 lanes/node x float4, 16 fully
// unrolled independent gathers, plain cached loads/stores.

#define LANES_PER_NODE 8
#define NODES_PER_BLOCK 32   // 256 threads / 8 lanes

__global__ __launch_bounds__(256) void seg_max_kernel(
    const float* __restrict__ x,
    const int* __restrict__ indptr,
    const int* __restrict__ indices,
    float* __restrict__ out,
    int n_nodes)
{
    const int c    = threadIdx.x & (LANES_PER_NODE - 1);   // float4 chunk 0..7
    const int node = blockIdx.x * NODES_PER_BLOCK + (threadIdx.x >> 3);
    if (node >= n_nodes) return;

    const int start = indptr[node];
    const int end   = indptr[node + 1];
    const int deg   = end - start;

    const float4* __restrict__ x4 = reinterpret_cast<const float4*>(x);

    float4 acc = make_float4(-INFINITY, -INFINITY, -INFINITY, -INFINITY);

    if (deg == 16 && ((start & 3) == 0)) {
        // Fast path: vector-load all 16 indices, fully unroll -> 16
        // independent dwordx4 gathers in flight per lane.
        const int4* __restrict__ idx4 =
            reinterpret_cast<const int4*>(indices + start);
        const int4 i0 = idx4[0];
        const int4 i1 = idx4[1];
        const int4 i2 = idx4[2];
        const int4 i3 = idx4[3];
        int rows[16] = { i0.x, i0.y, i0.z, i0.w,
                         i1.x, i1.y, i1.z, i1.w,
                         i2.x, i2.y, i2.z, i2.w,
                         i3.x, i3.y, i3.z, i3.w };
        #pragma unroll
        for (int e = 0; e < 16; ++e) {
            // rows[e] with compile-time e after full unroll -> stays in VGPRs.
            const float4 v = x4[rows[e] * LANES_PER_NODE + c];
            acc.x = fmaxf(acc.x, v.x);
            acc.y = fmaxf(acc.y, v.y);
            acc.z = fmaxf(acc.z, v.z);
            acc.w = fmaxf(acc.w, v.w);
        }
    } else {
        // Generic CSR fallback (correct for any degree / alignment).
        for (int e = start; e < end; ++e) {
            const int row = indices[e];
            const float4 v = x4[row * LANES_PER_NODE + c];
            acc.x = fmaxf(acc.x, v.x);
            acc.y = fmaxf(acc.y, v.y);
            acc.z = fmaxf(acc.z, v.z);
            acc.w = fmaxf(acc.w, v.w);
        }
    }

    reinterpret_cast<float4*>(out)[node * LANES_PER_NODE + c] = acc;
}

extern "C" void kernel_launch(void* const* d_in, const int* in_sizes, int n_in,
                              void* d_out, int out_size, void* d_ws, size_t ws_size,
                              hipStream_t stream) {
    const float* x       = (const float*)d_in[0];
    const int*   indptr  = (const int*)d_in[1];
    const int*   indices = (const int*)d_in[2];
    float*       out     = (float*)d_out;

    const int n_nodes = in_sizes[1] - 1;   // indptr has N+1 entries

    const int grid = (n_nodes + NODES_PER_BLOCK - 1) / NODES_PER_BLOCK;
    seg_max_kernel<<<grid, 256, 0, stream>>>(x, indptr, indices, out, n_nodes);
}